// Round 1
// baseline (502.149 us; speedup 1.0000x reference)
//
#include <hip/hip_runtime.h>
#include <hip/hip_bf16.h>
#include <math.h>

// GRUCell with adaptive-graph GCN on MI355X (gfx950).
// B=64, N=2048, Din=2, H=64, D=16, C=66, O=64.
// R9: (1) k_gemm -> T3-minimum 2-phase double-buffer (STAGE next tile before
//     compute, one __syncthreads/tile) + T1 XCD-chunked block swizzle.
//     (2) k_S + k_rowsm fused into k_attn (e fits LDS at D=16; S never hits HBM).
//     (3) k_e emits bf16 e copy into the dead-until-wmat workspace slot.

typedef __attribute__((ext_vector_type(4))) float f4;
typedef __attribute__((ext_vector_type(8))) short s8;  // 8 bf16 in 4 VGPRs (MFMA A/B frag)

#define B_   64
#define N_   2048
#define DIN  2
#define H_   64
#define D_   16
#define C_   66    // DIN + H
#define KI   132   // 2*C
#define KIP  160   // KI padded for K-loop (multiple of 32)
#define CB   4224  // B_*C_

#define GLD16(gp, lp) __builtin_amdgcn_global_load_lds((const __attribute__((address_space(1))) void*)(gp), (__attribute__((address_space(3))) void*)(lp), 16, 0, 0)

static __device__ __forceinline__ ushort f2bf(float v) {
  __hip_bfloat16 h = __float2bfloat16(v);
  return *(ushort*)&h;
}
static __device__ __forceinline__ float bf2f(ushort u) {
  __hip_bfloat16 h = *(__hip_bfloat16*)&u;
  return __bfloat162float(h);
}
static __device__ __forceinline__ uint packbf(float a, float b) {
  return ((uint)f2bf(b) << 16) | f2bf(a);
}

// ---------------------------------------------------------------- e = LN(node+time)*gamma+beta (fp32 + bf16 copies)
__global__ void k_e(const float* __restrict__ node, const float* __restrict__ timee,
                    const float* __restrict__ g0, const float* __restrict__ b0,
                    const float* __restrict__ g1, const float* __restrict__ b1,
                    const float* __restrict__ g2, const float* __restrict__ b2,
                    float* __restrict__ e, ushort* __restrict__ ebf) {
  int n = blockIdx.x * blockDim.x + threadIdx.x;
  if (n >= N_) return;
  float v[D_]; float m = 0.f;
  #pragma unroll
  for (int d = 0; d < D_; ++d) { v[d] = node[n * D_ + d] + timee[d]; m += v[d]; }
  m *= (1.0f / D_);
  float var = 0.f;
  #pragma unroll
  for (int d = 0; d < D_; ++d) { float t = v[d] - m; var += t * t; }
  var *= (1.0f / D_);
  float r = rsqrtf(var + 1e-12f);
  float y[D_];
  #pragma unroll
  for (int d = 0; d < D_; ++d) y[d] = (v[d] - m) * r;
  const float* gs[3] = {g0, g1, g2};
  const float* bs[3] = {b0, b1, b2};
  #pragma unroll
  for (int g = 0; g < 3; ++g) {
    #pragma unroll
    for (int d = 0; d < D_; d += 2) {
      float o0 = y[d] * gs[g][d] + bs[g][d];
      float o1 = y[d + 1] * gs[g][d + 1] + bs[g][d + 1];
      e[g * N_ * D_ + n * D_ + d] = o0;
      e[g * N_ * D_ + n * D_ + d + 1] = o1;
      *(uint*)&ebf[g * N_ * D_ + n * D_ + d] = packbf(o0, o1);
    }
  }
}

// ---------------------------------------------------------------- fused A_g = softmax(e_g e_g^T, axis=1), bf16
// One block = 16 output rows x full 2048 cols. Whole e_g (bf16, 64KB) lives in LDS;
// scores stay in registers (32 f4/wave), S never materialized.
__global__ __launch_bounds__(256)
void k_attn(const ushort* __restrict__ ebf, __hip_bfloat16* __restrict__ A) {
  __shared__ __align__(16) ushort eb[N_ * D_];   // 64 KB
  __shared__ float red[4][16];
  const int t = threadIdx.x;
  const ushort* eg = ebf + (size_t)blockIdx.z * (N_ * D_);
  {
    const uint4* src = (const uint4*)eg;
    uint4* dst = (uint4*)eb;
    #pragma unroll
    for (int i = 0; i < 16; ++i) dst[i * 256 + t] = src[i * 256 + t];
  }
  __syncthreads();
  const int lane = t & 63, w = t >> 6;
  const int l15 = lane & 15, q = lane >> 4;
  const int r0 = blockIdx.x * 16;
  // A-frag: lane l15 = output row, k = q*8.. (K=32, upper 16 zero-padded via exec mask)
  s8 af = {0, 0, 0, 0, 0, 0, 0, 0};
  if (q < 2) af = *(const s8*)&eb[(r0 + l15) * D_ + q * 8];
  const int c0 = w * 512;   // each wave owns 512 cols = 32 col-tiles
  f4 acc[32];
  #pragma unroll
  for (int tl = 0; tl < 32; ++tl) {
    s8 bfr = {0, 0, 0, 0, 0, 0, 0, 0};
    if (q < 2) bfr = *(const s8*)&eb[(c0 + tl * 16 + l15) * D_ + q * 8];
    acc[tl] = __builtin_amdgcn_mfma_f32_16x16x32_bf16(af, bfr, (f4)0.0f, 0, 0, 0);
  }
  // row max (rows q*4+rg): lane-local over tiles, shfl over l15, LDS over waves
  float pm[4], gm[4];
  #pragma unroll
  for (int rg = 0; rg < 4; ++rg) {
    float m = acc[0][rg];
    #pragma unroll
    for (int tl = 1; tl < 32; ++tl) m = fmaxf(m, acc[tl][rg]);
    m = fmaxf(m, __shfl_xor(m, 1, 64));
    m = fmaxf(m, __shfl_xor(m, 2, 64));
    m = fmaxf(m, __shfl_xor(m, 4, 64));
    m = fmaxf(m, __shfl_xor(m, 8, 64));
    pm[rg] = m;
  }
  if (l15 == 0) {
    #pragma unroll
    for (int rg = 0; rg < 4; ++rg) red[w][q * 4 + rg] = pm[rg];
  }
  __syncthreads();
  #pragma unroll
  for (int rg = 0; rg < 4; ++rg)
    gm[rg] = fmaxf(fmaxf(red[0][q * 4 + rg], red[1][q * 4 + rg]),
                   fmaxf(red[2][q * 4 + rg], red[3][q * 4 + rg]));
  __syncthreads();  // red reuse for sums
  float ps[4] = {0.f, 0.f, 0.f, 0.f};
  #pragma unroll
  for (int tl = 0; tl < 32; ++tl) {
    #pragma unroll
    for (int rg = 0; rg < 4; ++rg) {
      float v = __expf(acc[tl][rg] - gm[rg]);
      acc[tl][rg] = v;
      ps[rg] += v;
    }
  }
  #pragma unroll
  for (int rg = 0; rg < 4; ++rg) {
    float s = ps[rg];
    s += __shfl_xor(s, 1, 64);
    s += __shfl_xor(s, 2, 64);
    s += __shfl_xor(s, 4, 64);
    s += __shfl_xor(s, 8, 64);
    if (l15 == 0) red[w][q * 4 + rg] = s;
  }
  __syncthreads();
  float inv[4];
  #pragma unroll
  for (int rg = 0; rg < 4; ++rg)
    inv[rg] = 1.0f / (red[0][q * 4 + rg] + red[1][q * 4 + rg] +
                      red[2][q * 4 + rg] + red[3][q * 4 + rg]);
  ushort* Ar = (ushort*)A + (size_t)blockIdx.z * ((size_t)N_ * N_);
  #pragma unroll
  for (int tl = 0; tl < 32; ++tl) {
    #pragma unroll
    for (int rg = 0; rg < 4; ++rg)
      Ar[(size_t)(r0 + q * 4 + rg) * N_ + c0 + tl * 16 + l15] = f2bf(acc[tl][rg] * inv[rg]);
  }
}

// ---------------------------------------------------------------- X^T[j=b*C+c][m] bf16 via LDS transpose
template <int MODE>  // 0: xs=[x,state]   1: cand=[x, z*state]
__global__ __launch_bounds__(256)
void k_buildX(const float* __restrict__ x, const float* __restrict__ state,
              const __hip_bfloat16* __restrict__ zbuf, __hip_bfloat16* __restrict__ XT) {
  constexpr int LDM = 72;  // row stride (shorts), 144 B: 16B-aligned rows
  __shared__ __align__(16) ushort T[C_ * LDM];
  const int t = threadIdx.x;
  const int m0 = blockIdx.x * 64, b = blockIdx.y;
  const int m = t >> 2, hq = t & 3;
  {
    const float* sp = state + ((size_t)b * N_ + m0 + m) * H_ + hq * 16;
    float sv[16];
    #pragma unroll
    for (int i = 0; i < 16; i += 4) {
      float4 v = *(const float4*)(sp + i);
      sv[i] = v.x; sv[i + 1] = v.y; sv[i + 2] = v.z; sv[i + 3] = v.w;
    }
    if (MODE) {
      const ushort* zp = (const ushort*)zbuf + ((size_t)b * N_ + m0 + m) * H_ + hq * 16;
      uint4 z0 = *(const uint4*)&zp[0], z1 = *(const uint4*)&zp[8];
      uint zw[8] = {z0.x, z0.y, z0.z, z0.w, z1.x, z1.y, z1.z, z1.w};
      #pragma unroll
      for (int i = 0; i < 8; ++i) {
        sv[2 * i]     *= bf2f((ushort)(zw[i] & 0xffffu));
        sv[2 * i + 1] *= bf2f((ushort)(zw[i] >> 16));
      }
    }
    #pragma unroll
    for (int i = 0; i < 16; ++i) T[(DIN + hq * 16 + i) * LDM + m] = f2bf(sv[i]);
    if (t < 64) {
      const float2 xv = *(const float2*)&x[((size_t)b * N_ + m0 + t) * DIN];
      T[0 * LDM + t] = f2bf(xv.x);
      T[1 * LDM + t] = f2bf(xv.y);
    }
  }
  __syncthreads();
  {
    int r = t >> 2, ch = t & 3;
    ushort* dst = (ushort*)XT + (size_t)(b * C_ + r) * N_ + m0 + ch * 16;
    *(uint4*)&dst[0] = *(uint4*)&T[r * LDM + ch * 16];
    *(uint4*)&dst[8] = *(uint4*)&T[r * LDM + ch * 16 + 8];
    if (t < 8) {
      r = 64 + (t >> 2);
      ushort* dst2 = (ushort*)XT + (size_t)(b * C_ + r) * N_ + m0 + ch * 16;
      *(uint4*)&dst2[0] = *(uint4*)&T[r * LDM + ch * 16];
      *(uint4*)&dst2[8] = *(uint4*)&T[r * LDM + ch * 16 + 8];
    }
  }
}

// ---------------------------------------------------------------- Y[r,j] = sum_m A[r,m] XT[j,m]
// R9: 2-phase double-buffered staging (issue next tile BEFORE compute, one barrier
// per tile) + XCD-chunked bijective block swizzle (nwg % 8 == 0 for all launches).
__global__ __launch_bounds__(256)
void k_gemm(const __hip_bfloat16* __restrict__ Abase, size_t astride,
            const __hip_bfloat16* __restrict__ XT,
            __hip_bfloat16* __restrict__ Ybase, size_t ystride) {
  __shared__ __align__(16) ushort At[2][128 * 32];
  __shared__ __align__(16) ushort Xt[2][128 * 32];
  const int t = threadIdx.x;
  // T1: each XCD gets a contiguous chunk of tiles -> its 4 A row-panels stay L2-resident.
  const int nwg = gridDim.x * gridDim.y * gridDim.z;   // 1056 or 528, both %8==0
  const int orig = blockIdx.x + gridDim.x * (blockIdx.y + gridDim.y * blockIdx.z);
  const int chunk = nwg >> 3;
  const int swz = (orig & 7) * chunk + (orig >> 3);
  const int bx = swz % gridDim.x;
  const int rest = swz / gridDim.x;
  const int by = rest % gridDim.y;
  const int bz = rest / gridDim.y;
  const int j0 = bx * 128, r0 = by * 128;
  const ushort* Ag = (const ushort*)Abase + (size_t)bz * astride;
  ushort* Y = (ushort*)Ybase + (size_t)bz * ystride;
  const int lane = t & 63, w = t >> 6;
  const int rowa = w * 32 + (lane >> 2), kc = (lane & 3) * 8;
  const ushort* gA = Ag + (size_t)(r0 + rowa) * N_ + kc;
  const ushort* gX = (const ushort*)XT + (size_t)(j0 + rowa) * N_ + kc;
  const int l15 = t & 15, q = (t >> 4) & 3;
  const int wr = (w >> 1) * 64, wc = (w & 1) * 64;
  f4 acc[4][4];
  #pragma unroll
  for (int i = 0; i < 4; ++i)
    #pragma unroll
    for (int jj = 0; jj < 4; ++jj) acc[i][jj] = (f4)0.0f;
  // prologue: stage tile 0 into buffer 0
  GLD16(gA, &At[0][(w * 32) * 32]);
  GLD16(gA + 16 * N_, &At[0][(w * 32 + 16) * 32]);
  GLD16(gX, &Xt[0][(w * 32) * 32]);
  GLD16(gX + 16 * N_, &Xt[0][(w * 32 + 16) * 32]);
  __syncthreads();   // vmcnt(0) drain -> buf0 ready
  int cur = 0;
  for (int k0 = 0; k0 < N_; k0 += 32) {
    const int kn = k0 + 32;
    if (kn < N_) {   // issue next tile's loads; latency hides under this tile's MFMA
      const int nx = cur ^ 1;
      GLD16(gA + kn, &At[nx][(w * 32) * 32]);
      GLD16(gA + 16 * N_ + kn, &At[nx][(w * 32 + 16) * 32]);
      GLD16(gX + kn, &Xt[nx][(w * 32) * 32]);
      GLD16(gX + 16 * N_ + kn, &Xt[nx][(w * 32 + 16) * 32]);
    }
    s8 af[4], bfr[4];
    #pragma unroll
    for (int mi = 0; mi < 4; ++mi) af[mi] = *(const s8*)&At[cur][(wr + mi * 16 + l15) * 32 + q * 8];
    #pragma unroll
    for (int ni = 0; ni < 4; ++ni) bfr[ni] = *(const s8*)&Xt[cur][(wc + ni * 16 + l15) * 32 + q * 8];
    #pragma unroll
    for (int mi = 0; mi < 4; ++mi)
      #pragma unroll
      for (int ni = 0; ni < 4; ++ni)
        acc[mi][ni] = __builtin_amdgcn_mfma_f32_16x16x32_bf16(af[mi], bfr[ni], acc[mi][ni], 0, 0, 0);
    __syncthreads();  // drains prefetch (vmcnt 0) + guards buf[cur] reuse next iter
    cur ^= 1;
  }
  // C/D: col = lane&15, row = quad*4 + reg  [verified m89/m91]
  #pragma unroll
  for (int mi = 0; mi < 4; ++mi) {
    int rr = r0 + wr + mi * 16 + q * 4;
    #pragma unroll
    for (int ni = 0; ni < 4; ++ni) {
      int cc = j0 + wc + ni * 16 + l15;
      #pragma unroll
      for (int rg = 0; rg < 4; ++rg)
        Y[(size_t)(rr + rg) * CB + cc] = f2bf(acc[mi][ni][rg]);
    }
  }
}

// ---------------------------------------------------------------- Wm[n][o][KIP] bf16 = sum_d e[n,d] Wp[d,ki,o]
__global__ __launch_bounds__(256)
void k_wmat(const float* __restrict__ eg, const float* __restrict__ Wp, ushort* __restrict__ Wm) {
  constexpr int TRS = 36;  // Tr row stride (shorts)
  __shared__ float Wl[16 * 8 * 64];     // [d][kr][o]  32 KB
  __shared__ ushort Tr[8 * 64 * TRS];   // [n][o][36]
  const int t = threadIdx.x;
  const int n0 = blockIdx.x * 8;
  const int y = blockIdx.y;             // ki-quarter; y==3 covers kic 12..19 (incl. zero tail)
  const int o = t & 63, w = t >> 6;
  const int ng = w & 1, krh = (w >> 1) * 4;
  float er[4][16];
  #pragma unroll
  for (int j = 0; j < 4; ++j) {
    const float* ep = eg + (size_t)(n0 + ng * 4 + j) * D_;
    #pragma unroll
    for (int d = 0; d < D_; d += 4) {
      float4 v = *(const float4*)(ep + d);
      er[j][d] = v.x; er[j][d + 1] = v.y; er[j][d + 2] = v.z; er[j][d + 3] = v.w;
    }
  }
  const int ngroups = (y == 3) ? 2 : 1;
  for (int g = 0; g < ngroups; ++g) {
    const int kic0 = y * 4 + g * 4;
    for (int kk = 0; kk < 4; ++kk) {
      const int kic = kic0 + kk;
      __syncthreads();
      #pragma unroll
      for (int it = 0; it < 8; ++it) {
        int f = it * 256 + t;
        int d = f >> 7, rem = f & 127, kr = rem >> 4, o4 = rem & 15;
        int ki = kic * 8 + kr;
        float4 v;
        if (ki < KI) v = *(const float4*)&Wp[((size_t)d * KI + ki) * 64 + o4 * 4];
        else { v.x = 0.f; v.y = 0.f; v.z = 0.f; v.w = 0.f; }
        *(float4*)&Wl[f * 4] = v;
      }
      __syncthreads();
      float a[4][4];
      #pragma unroll
      for (int j = 0; j < 4; ++j)
        #pragma unroll
        for (int k = 0; k < 4; ++k) a[j][k] = 0.f;
      for (int d = 0; d < D_; ++d) {
        float w4[4];
        #pragma unroll
        for (int k = 0; k < 4; ++k) w4[k] = Wl[(d * 8 + krh + k) * 64 + o];
        #pragma unroll
        for (int j = 0; j < 4; ++j)
          #pragma unroll
          for (int k = 0; k < 4; ++k) a[j][k] = fmaf(er[j][d], w4[k], a[j][k]);
      }
      #pragma unroll
      for (int j = 0; j < 4; ++j) {
        ushort* tr = &Tr[((ng * 4 + j) * 64 + o) * TRS + kk * 8 + krh];
        *(uint*)&tr[0] = packbf(a[j][0], a[j][1]);
        *(uint*)&tr[2] = packbf(a[j][2], a[j][3]);
      }
    }
    __syncthreads();
    const int k0 = kic0 * 8;
    #pragma unroll
    for (int p = 0; p < 8; ++p) {
      int u = p * 256 + t;
      int nl = u >> 8, oo = (u >> 2) & 63, qq = u & 3;
      const ushort* tr = &Tr[(nl * 64 + oo) * TRS + qq * 8];
      uint2 lo = *(const uint2*)&tr[0];
      uint2 hi = *(const uint2*)&tr[4];
      uint4 vv; vv.x = lo.x; vv.y = lo.y; vv.z = hi.x; vv.w = hi.y;
      *(uint4*)&Wm[((size_t)(n0 + nl) * 64 + oo) * KIP + k0 + qq * 8] = vv;
    }
  }
}

// ---------------------------------------------------------------- per-node einsum via MFMA; B-frags direct from global Wm
template <int MODE>  // 0: sigmoid -> bf16 gate buf ; 1: tanh + GRU combine -> fp32 d_out
__global__ __launch_bounds__(256)
void k_einsum(const float* __restrict__ e, const ushort* __restrict__ Wm, const float* __restrict__ bp,
              const __hip_bfloat16* __restrict__ Y,
              const float* __restrict__ x, const float* __restrict__ state,
              const __hip_bfloat16* __restrict__ zbuf, const __hip_bfloat16* __restrict__ rbuf,
              void* __restrict__ outp) {
  constexpr int LDK = 168;
  constexpr int LDR = 72;
  __shared__ __align__(16) ushort xg[64 * LDK];
  __shared__ __align__(16) ushort res[64 * LDR];
  __shared__ float el[D_];
  __shared__ float bl[64];
  const int n = blockIdx.x, t = threadIdx.x;
  if (t < D_) el[t] = e[n * D_ + t];
  __syncthreads();
  if (t < 64) {
    float s = 0.f;
    #pragma unroll
    for (int d = 0; d < D_; ++d) s += el[d] * bp[d * 64 + t];
    bl[t] = s;
  }
  {
    const int b = t >> 2, j = t & 3;
    const size_t bn = (size_t)b * N_ + n;
    float sv[16];
    const float* sp = state + bn * 64 + j * 16;
    #pragma unroll
    for (int i = 0; i < 16; i += 4) {
      float4 v = *(const float4*)(sp + i);
      sv[i] = v.x; sv[i + 1] = v.y; sv[i + 2] = v.z; sv[i + 3] = v.w;
    }
    if (MODE) {
      const ushort* zp = (const ushort*)zbuf + bn * 64 + j * 16;
      uint4 z0 = *(const uint4*)&zp[0], z1 = *(const uint4*)&zp[8];
      uint zw[8] = {z0.x, z0.y, z0.z, z0.w, z1.x, z1.y, z1.z, z1.w};
      #pragma unroll
      for (int i = 0; i < 8; ++i) {
        sv[2 * i]     *= bf2f((ushort)(zw[i] & 0xffffu));
        sv[2 * i + 1] *= bf2f((ushort)(zw[i] >> 16));
      }
    }
    ushort* xr = &xg[b * LDK + 2 + j * 16];
    #pragma unroll
    for (int i = 0; i < 16; i += 2) {
      uint pk = packbf(sv[i], sv[i + 1]);
      *(uint*)&xr[i] = pk;
    }
    const ushort* yp = (const ushort*)Y + (size_t)n * CB + b * C_ + j * 16;
    uint* xy = (uint*)&xg[b * LDK + 66 + j * 16];
    #pragma unroll
    for (int i = 0; i < 8; ++i) xy[i] = *(const uint*)&yp[2 * i];
    if (j == 0) *(uint*)&xg[b * LDK + 130] = *(const uint*)&yp[64];
    if (t < 64) {
      const float* xp = x + ((size_t)t * N_ + n) * DIN;
      uint pk = packbf(xp[0], xp[1]);
      *(uint*)&xg[t * LDK] = pk;
    }
    ushort* pg = &xg[b * LDK + 132 + j * 7];
    #pragma unroll
    for (int i = 0; i < 7; ++i) pg[i] = 0;
  }
  __syncthreads();
  const int l15 = t & 15, q = (t >> 4) & 3, w = t >> 6;
  const int wm = (w >> 1) * 32, wn = (w & 1) * 32;
  const ushort* Wn = Wm + (size_t)n * (64 * KIP);
  f4 acc[2][2];
  acc[0][0] = acc[0][1] = acc[1][0] = acc[1][1] = (f4)0.0f;
  #pragma unroll
  for (int kk = 0; kk < KIP; kk += 32) {
    s8 af[2], bfr[2];
    #pragma unroll
    for (int mi = 0; mi < 2; ++mi) af[mi] = *(const s8*)&xg[(wm + mi * 16 + l15) * LDK + kk + q * 8];
    #pragma unroll
    for (int ni = 0; ni < 2; ++ni) bfr[ni] = *(const s8*)(Wn + (size_t)(wn + ni * 16 + l15) * KIP + kk + q * 8);
    #pragma unroll
    for (int mi = 0; mi < 2; ++mi)
      #pragma unroll
      for (int ni = 0; ni < 2; ++ni)
        acc[mi][ni] = __builtin_amdgcn_mfma_f32_16x16x32_bf16(af[mi], bfr[ni], acc[mi][ni], 0, 0, 0);
  }
  {
    float bl0 = bl[wn + l15], bl1 = bl[wn + 16 + l15];
    #pragma unroll
    for (int mi = 0; mi < 2; ++mi)
      #pragma unroll
      for (int ni = 0; ni < 2; ++ni) {
        float bb = ni ? bl1 : bl0;
        #pragma unroll
        for (int rg = 0; rg < 4; ++rg) {
          float v = acc[mi][ni][rg] + bb;
          float a;
          if (MODE == 0) a = 1.0f / (1.0f + __expf(-v));
          else           a = 1.0f - 2.0f / (__expf(2.0f * v) + 1.0f);
          res[(wm + mi * 16 + q * 4 + rg) * LDR + (wn + ni * 16 + l15)] = f2bf(a);
        }
      }
  }
  __syncthreads();
  {
    const int b = t >> 2, j = t & 3;
    const size_t gb = ((size_t)b * N_ + n) * 64 + j * 16;
    const ushort* rr = &res[b * LDR + j * 16];
    if (MODE == 0) {
      uint4 v0 = *(const uint4*)&rr[0];
      uint4 v1 = *(const uint4*)&rr[8];
      *(uint4*)((ushort*)outp + gb) = v0;
      *(uint4*)((ushort*)outp + gb + 8) = v1;
    } else {
      float* ob = (float*)outp;
      const float* stp = state + gb;
      const ushort* rp = (const ushort*)rbuf + gb;
      uint4 r0 = *(const uint4*)&rp[0], r1 = *(const uint4*)&rp[8];
      uint rw[8] = {r0.x, r0.y, r0.z, r0.w, r1.x, r1.y, r1.z, r1.w};
      #pragma unroll
      for (int i = 0; i < 16; i += 4) {
        float4 st = *(const float4*)(stp + i);
        float4 ov;
        float rv0 = bf2f((ushort)(rw[i / 2] & 0xffffu));
        float rv1 = bf2f((ushort)(rw[i / 2] >> 16));
        float rv2 = bf2f((ushort)(rw[i / 2 + 1] & 0xffffu));
        float rv3 = bf2f((ushort)(rw[i / 2 + 1] >> 16));
        ov.x = rv0 * st.x + (1.0f - rv0) * bf2f(rr[i]);
        ov.y = rv1 * st.y + (1.0f - rv1) * bf2f(rr[i + 1]);
        ov.z = rv2 * st.z + (1.0f - rv2) * bf2f(rr[i + 2]);
        ov.w = rv3 * st.w + (1.0f - rv3) * bf2f(rr[i + 3]);
        *(float4*)(ob + gb + i) = ov;
      }
    }
  }
}

// ----------------------------------------------------------------
extern "C" void kernel_launch(void* const* d_in, const int* in_sizes, int n_in,
                              void* d_out, int out_size, void* d_ws, size_t ws_size,
                              hipStream_t stream) {
  const float* x     = (const float*)d_in[0];
  const float* state = (const float*)d_in[1];
  const float* node  = (const float*)d_in[2];
  const float* timee = (const float*)d_in[3];
  const float* W_z = (const float*)d_in[4];
  const float* b_z = (const float*)d_in[5];
  const float* g_z = (const float*)d_in[6];
  const float* be_z = (const float*)d_in[7];
  const float* W_r = (const float*)d_in[8];
  const float* b_r = (const float*)d_in[9];
  const float* g_r = (const float*)d_in[10];
  const float* be_r = (const float*)d_in[11];
  const float* W_u = (const float*)d_in[12];
  const float* b_u = (const float*)d_in[13];
  const float* g_u = (const float*)d_in[14];
  const float* be_u = (const float*)d_in[15];

  constexpr size_t NN = (size_t)N_ * N_;
  constexpr size_t ND = (size_t)N_ * D_;
  // Workspace layout (bytes):
  char* ws = (char*)d_ws;
  float*           e  = (float*)(ws);                        //       0 :    393,216
  __hip_bfloat16*  A  = (__hip_bfloat16*)(ws + 393216);      //  25,165,824
  __hip_bfloat16*  XT = (__hip_bfloat16*)(ws + 25559040);    //  17,301,504
  __hip_bfloat16*  Y  = (__hip_bfloat16*)(ws + 42860544);    //  17,301,504 (Y_z; also reused for u)
  __hip_bfloat16*  zb = (__hip_bfloat16*)(ws + 60162048);    //  16,777,216
  __hip_bfloat16*  rb = (__hip_bfloat16*)(ws + 76939264);    //  16,777,216
  ushort*          ebf = (ushort*)(ws + 93716480);           //  196,608 (dead before Wm written)
  ushort*          Wm = (ushort*)(ws + 93716480);            //  41,943,040 (ends 135,659,520)
  __hip_bfloat16*  Yr = (__hip_bfloat16*)(ws + 135659520);   //  17,301,504 (big-ws only; ends 152,961,024)
  const size_t YRD = ((size_t)135659520 - 42860544) / 2;     // Y_z -> Y_r element delta
  const bool big = ws_size >= (size_t)152961024;

  float* out = (float*)d_out;

  k_e<<<8, 256, 0, stream>>>(node, timee, g_z, be_z, g_r, be_r, g_u, be_u, e, ebf);
  // fused S+softmax: no S materialization, one dispatch for all 3 gates
  k_attn<<<dim3(N_ / 16, 1, 3), 256, 0, stream>>>(ebf, A);
  k_buildX<0><<<dim3(32, 64), 256, 0, stream>>>(x, state, nullptr, XT);

  dim3 ggrid1(CB / 128, N_ / 128, 1);   // 528 blocks (%8==0)
  dim3 ggrid2(CB / 128, N_ / 128, 2);   // fused z+r: 1056 blocks (%8==0)
  dim3 wgrid(N_ / 8, 4);                // 1024 blocks

  if (big) {
    k_wmat<<<wgrid, 256, 0, stream>>>(e + 0 * ND, W_z, Wm);
    k_gemm<<<ggrid2, 256, 0, stream>>>(A, NN, XT, Y, YRD);                       // z->Y, r->Yr
    k_einsum<0><<<N_, 256, 0, stream>>>(e + 0 * ND, Wm, b_z, Y, x, state, nullptr, nullptr, (void*)zb);
    k_wmat<<<wgrid, 256, 0, stream>>>(e + 1 * ND, W_r, Wm);
    k_einsum<0><<<N_, 256, 0, stream>>>(e + 1 * ND, Wm, b_r, Yr, x, state, nullptr, nullptr, (void*)rb);
  } else {
    k_wmat<<<wgrid, 256, 0, stream>>>(e + 0 * ND, W_z, Wm);
    k_gemm<<<ggrid1, 256, 0, stream>>>(A, 0, XT, Y, 0);
    k_einsum<0><<<N_, 256, 0, stream>>>(e + 0 * ND, Wm, b_z, Y, x, state, nullptr, nullptr, (void*)zb);
    k_wmat<<<wgrid, 256, 0, stream>>>(e + 1 * ND, W_r, Wm);
    k_gemm<<<ggrid1, 256, 0, stream>>>(A + NN, 0, XT, Y, 0);
    k_einsum<0><<<N_, 256, 0, stream>>>(e + 1 * ND, Wm, b_r, Y, x, state, nullptr, nullptr, (void*)rb);
  }
  // gate u: cand = [x, z*state]
  k_buildX<1><<<dim3(32, 64), 256, 0, stream>>>(x, state, zb, XT);
  k_wmat<<<wgrid, 256, 0, stream>>>(e + 2 * ND, W_u, Wm);
  k_gemm<<<ggrid1, 256, 0, stream>>>(A + 2 * NN, 0, XT, Y, 0);
  k_einsum<1><<<N_, 256, 0, stream>>>(e + 2 * ND, Wm, b_u, Y, x, state, zb, rb, (void*)out);
}

// Round 2
// 486.256 us; speedup vs baseline: 1.0327x; 1.0327x over previous
//
#include <hip/hip_runtime.h>
#include <hip/hip_bf16.h>
#include <math.h>

// GRUCell with adaptive-graph GCN on MI355X (gfx950).
// B=64, N=2048, Din=2, H=64, D=16, C=66, O=64.
// R10: (1) k_gemm -> TRUE pipelined dbuf: counted vmcnt(4) + raw s_barrier
//      (T4; __syncthreads drains vmcnt(0) and kills the pipeline), T2
//      both-sides LDS swizzle (pre-swizzled global source granule + swizzled
//      ds_read granule; kills the structural 8-way conflict 8.65M->~0),
//      T5 setprio around MFMA, running pointers for staging addresses.
//      (2) k_attn -> swapped-operand MFMA (lane holds row r0+l15, 4 consecutive
//      cols q*4+rg) => packed uint2 stores + 2-shfl row reductions.

typedef __attribute__((ext_vector_type(4))) float f4;
typedef __attribute__((ext_vector_type(8))) short s8;  // 8 bf16 in 4 VGPRs (MFMA A/B frag)

#define B_   64
#define N_   2048
#define DIN  2
#define H_   64
#define D_   16
#define C_   66    // DIN + H
#define KI   132   // 2*C
#define KIP  160   // KI padded for K-loop (multiple of 32)
#define CB   4224  // B_*C_

#define GLD16(gp, lp) __builtin_amdgcn_global_load_lds((const __attribute__((address_space(1))) void*)(gp), (__attribute__((address_space(3))) void*)(lp), 16, 0, 0)

static __device__ __forceinline__ ushort f2bf(float v) {
  __hip_bfloat16 h = __float2bfloat16(v);
  return *(ushort*)&h;
}
static __device__ __forceinline__ float bf2f(ushort u) {
  __hip_bfloat16 h = *(__hip_bfloat16*)&u;
  return __bfloat162float(h);
}
static __device__ __forceinline__ uint packbf(float a, float b) {
  return ((uint)f2bf(b) << 16) | f2bf(a);
}

// ---------------------------------------------------------------- e = LN(node+time)*gamma+beta (fp32 + bf16 copies)
__global__ void k_e(const float* __restrict__ node, const float* __restrict__ timee,
                    const float* __restrict__ g0, const float* __restrict__ b0,
                    const float* __restrict__ g1, const float* __restrict__ b1,
                    const float* __restrict__ g2, const float* __restrict__ b2,
                    float* __restrict__ e, ushort* __restrict__ ebf) {
  int n = blockIdx.x * blockDim.x + threadIdx.x;
  if (n >= N_) return;
  float v[D_]; float m = 0.f;
  #pragma unroll
  for (int d = 0; d < D_; ++d) { v[d] = node[n * D_ + d] + timee[d]; m += v[d]; }
  m *= (1.0f / D_);
  float var = 0.f;
  #pragma unroll
  for (int d = 0; d < D_; ++d) { float t = v[d] - m; var += t * t; }
  var *= (1.0f / D_);
  float r = rsqrtf(var + 1e-12f);
  float y[D_];
  #pragma unroll
  for (int d = 0; d < D_; ++d) y[d] = (v[d] - m) * r;
  const float* gs[3] = {g0, g1, g2};
  const float* bs[3] = {b0, b1, b2};
  #pragma unroll
  for (int g = 0; g < 3; ++g) {
    #pragma unroll
    for (int d = 0; d < D_; d += 2) {
      float o0 = y[d] * gs[g][d] + bs[g][d];
      float o1 = y[d + 1] * gs[g][d + 1] + bs[g][d + 1];
      e[g * N_ * D_ + n * D_ + d] = o0;
      e[g * N_ * D_ + n * D_ + d + 1] = o1;
      *(uint*)&ebf[g * N_ * D_ + n * D_ + d] = packbf(o0, o1);
    }
  }
}

// ---------------------------------------------------------------- fused A_g = softmax(e_g e_g^T, axis=1), bf16
// Swapped operands: acc = mfma(e_cols, e_rows) => lane (l15,q) holds
// S[r0+l15, c0 + tl*16 + q*4 + rg] — 4 consecutive cols per lane.
__global__ __launch_bounds__(256)
void k_attn(const ushort* __restrict__ ebf, __hip_bfloat16* __restrict__ A) {
  __shared__ __align__(16) ushort eb[N_ * D_];   // 64 KB
  __shared__ float red[4][16];
  const int t = threadIdx.x;
  const ushort* eg = ebf + (size_t)blockIdx.z * (N_ * D_);
  {
    const uint4* src = (const uint4*)eg;
    uint4* dst = (uint4*)eb;
    #pragma unroll
    for (int i = 0; i < 16; ++i) dst[i * 256 + t] = src[i * 256 + t];
  }
  __syncthreads();
  const int lane = t & 63, w = t >> 6;
  const int l15 = lane & 15, q = lane >> 4;
  const int r0 = blockIdx.x * 16;
  // rows frag (B operand): lane l15 = output row r0+l15
  s8 rf = {0, 0, 0, 0, 0, 0, 0, 0};
  if (q < 2) rf = *(const s8*)&eb[(r0 + l15) * D_ + q * 8];
  const int c0 = w * 512;   // each wave owns 512 cols = 32 col-tiles
  f4 acc[32];
  #pragma unroll
  for (int tl = 0; tl < 32; ++tl) {
    s8 cf = {0, 0, 0, 0, 0, 0, 0, 0};   // cols frag (A operand): lane l15 = col tl*16+l15
    if (q < 2) cf = *(const s8*)&eb[(c0 + tl * 16 + l15) * D_ + q * 8];
    acc[tl] = __builtin_amdgcn_mfma_f32_16x16x32_bf16(cf, rf, (f4)0.0f, 0, 0, 0);
  }
  // row max: lane-local over 128 values, then combine q-lanes (xor 16,32), then waves
  float m = acc[0][0];
  #pragma unroll
  for (int tl = 0; tl < 32; ++tl) {
    #pragma unroll
    for (int rg = 0; rg < 4; ++rg) m = fmaxf(m, acc[tl][rg]);
  }
  m = fmaxf(m, __shfl_xor(m, 16, 64));
  m = fmaxf(m, __shfl_xor(m, 32, 64));
  if (lane < 16) red[w][l15] = m;
  __syncthreads();
  const float gm = fmaxf(fmaxf(red[0][l15], red[1][l15]), fmaxf(red[2][l15], red[3][l15]));
  __syncthreads();  // red reuse for sums
  float ps = 0.f;
  #pragma unroll
  for (int tl = 0; tl < 32; ++tl) {
    #pragma unroll
    for (int rg = 0; rg < 4; ++rg) {
      float v = __expf(acc[tl][rg] - gm);
      acc[tl][rg] = v;
      ps += v;
    }
  }
  ps += __shfl_xor(ps, 16, 64);
  ps += __shfl_xor(ps, 32, 64);
  if (lane < 16) red[w][l15] = ps;
  __syncthreads();
  const float inv = 1.0f / (red[0][l15] + red[1][l15] + red[2][l15] + red[3][l15]);
  ushort* Ar = (ushort*)A + (size_t)blockIdx.z * ((size_t)N_ * N_) +
               (size_t)(r0 + l15) * N_ + c0 + q * 4;
  #pragma unroll
  for (int tl = 0; tl < 32; ++tl) {
    uint2 pk;
    pk.x = packbf(acc[tl][0] * inv, acc[tl][1] * inv);
    pk.y = packbf(acc[tl][2] * inv, acc[tl][3] * inv);
    *(uint2*)&Ar[tl * 16] = pk;
  }
}

// ---------------------------------------------------------------- X^T[j=b*C+c][m] bf16 via LDS transpose
template <int MODE>  // 0: xs=[x,state]   1: cand=[x, z*state]
__global__ __launch_bounds__(256)
void k_buildX(const float* __restrict__ x, const float* __restrict__ state,
              const __hip_bfloat16* __restrict__ zbuf, __hip_bfloat16* __restrict__ XT) {
  constexpr int LDM = 72;  // row stride (shorts), 144 B: 16B-aligned rows
  __shared__ __align__(16) ushort T[C_ * LDM];
  const int t = threadIdx.x;
  const int m0 = blockIdx.x * 64, b = blockIdx.y;
  const int m = t >> 2, hq = t & 3;
  {
    const float* sp = state + ((size_t)b * N_ + m0 + m) * H_ + hq * 16;
    float sv[16];
    #pragma unroll
    for (int i = 0; i < 16; i += 4) {
      float4 v = *(const float4*)(sp + i);
      sv[i] = v.x; sv[i + 1] = v.y; sv[i + 2] = v.z; sv[i + 3] = v.w;
    }
    if (MODE) {
      const ushort* zp = (const ushort*)zbuf + ((size_t)b * N_ + m0 + m) * H_ + hq * 16;
      uint4 z0 = *(const uint4*)&zp[0], z1 = *(const uint4*)&zp[8];
      uint zw[8] = {z0.x, z0.y, z0.z, z0.w, z1.x, z1.y, z1.z, z1.w};
      #pragma unroll
      for (int i = 0; i < 8; ++i) {
        sv[2 * i]     *= bf2f((ushort)(zw[i] & 0xffffu));
        sv[2 * i + 1] *= bf2f((ushort)(zw[i] >> 16));
      }
    }
    #pragma unroll
    for (int i = 0; i < 16; ++i) T[(DIN + hq * 16 + i) * LDM + m] = f2bf(sv[i]);
    if (t < 64) {
      const float2 xv = *(const float2*)&x[((size_t)b * N_ + m0 + t) * DIN];
      T[0 * LDM + t] = f2bf(xv.x);
      T[1 * LDM + t] = f2bf(xv.y);
    }
  }
  __syncthreads();
  {
    int r = t >> 2, ch = t & 3;
    ushort* dst = (ushort*)XT + (size_t)(b * C_ + r) * N_ + m0 + ch * 16;
    *(uint4*)&dst[0] = *(uint4*)&T[r * LDM + ch * 16];
    *(uint4*)&dst[8] = *(uint4*)&T[r * LDM + ch * 16 + 8];
    if (t < 8) {
      r = 64 + (t >> 2);
      ushort* dst2 = (ushort*)XT + (size_t)(b * C_ + r) * N_ + m0 + ch * 16;
      *(uint4*)&dst2[0] = *(uint4*)&T[r * LDM + ch * 16];
      *(uint4*)&dst2[8] = *(uint4*)&T[r * LDM + ch * 16 + 8];
    }
  }
}

// ---------------------------------------------------------------- Y[r,j] = sum_m A[r,m] XT[j,m]
// R10: counted-vmcnt pipelined dbuf (loads stay in flight across raw barriers),
// T2 both-sides swizzle, T5 setprio, T1 XCD-chunked swizzle.
__global__ __launch_bounds__(256)
void k_gemm(const __hip_bfloat16* __restrict__ Abase, size_t astride,
            const __hip_bfloat16* __restrict__ XT,
            __hip_bfloat16* __restrict__ Ybase, size_t ystride) {
  __shared__ __align__(16) ushort At[2][128 * 32];
  __shared__ __align__(16) ushort Xt[2][128 * 32];
  const int t = threadIdx.x;
  // T1: each XCD gets a contiguous chunk of tiles -> A row-panels stay L2-resident.
  const int nwg = gridDim.x * gridDim.y * gridDim.z;   // 1056 or 528, both %8==0
  const int orig = blockIdx.x + gridDim.x * (blockIdx.y + gridDim.y * blockIdx.z);
  const int chunk = nwg >> 3;
  const int swz = (orig & 7) * chunk + (orig >> 3);
  const int bx = swz % gridDim.x;
  const int rest = swz / gridDim.x;
  const int by = rest % gridDim.y;
  const int bz = rest / gridDim.y;
  const int j0 = bx * 128, r0 = by * 128;
  const ushort* Ag = (const ushort*)Abase + (size_t)bz * astride;
  ushort* Y = (ushort*)Ybase + (size_t)bz * ystride;
  const int lane = t & 63, w = t >> 6;
  const int rowa = w * 32 + (lane >> 2);
  // T2 write side: LDS dest is linear (base + lane*16B); pre-swizzle the GLOBAL
  // source granule so LDS slot (row, g) holds global granule g ^ ((row>>1)&3).
  // Same 64B cache line per 4-lane row group -> zero coalescing loss.
  const int kc = (((lane & 3) ^ ((lane >> 3) & 3)) * 8);
  const ushort* pA0 = Ag + (size_t)(r0 + rowa) * N_ + kc;
  const ushort* pA1 = pA0 + 16 * N_;
  const ushort* pX0 = (const ushort*)XT + (size_t)(j0 + rowa) * N_ + kc;
  const ushort* pX1 = pX0 + 16 * N_;
  const int l15 = t & 15, q = (t >> 4) & 3;
  // T2 read side: granule q' = q ^ ((row>>1)&3); frag rows are multiples of 16
  // plus l15, so the row-dependence reduces to l15.
  const int qs = (q ^ ((l15 >> 1) & 3)) * 8;
  const int wr = (w >> 1) * 64, wc = (w & 1) * 64;
  f4 acc[4][4];
  #pragma unroll
  for (int i = 0; i < 4; ++i)
    #pragma unroll
    for (int jj = 0; jj < 4; ++jj) acc[i][jj] = (f4)0.0f;
  // prologue: stage tile 0 into buffer 0 (4 loads in flight)
  GLD16(pA0, &At[0][(w * 32) * 32]);
  GLD16(pA1, &At[0][(w * 32 + 16) * 32]);
  GLD16(pX0, &Xt[0][(w * 32) * 32]);
  GLD16(pX1, &Xt[0][(w * 32 + 16) * 32]);
  pA0 += 32; pA1 += 32; pX0 += 32; pX1 += 32;
  int cur = 0;
  for (int k0 = 0; k0 < N_; k0 += 32) {
    if (k0 + 32 < N_) {
      // issue next tile (8 in flight), then wait for the 4 OLDER (cur's) only.
      // buf[cur^1] overwrite is safe: all reads of it completed before the
      // trailing barrier of the previous iteration.
      const int nx = cur ^ 1;
      GLD16(pA0, &At[nx][(w * 32) * 32]);
      GLD16(pA1, &At[nx][(w * 32 + 16) * 32]);
      GLD16(pX0, &Xt[nx][(w * 32) * 32]);
      GLD16(pX1, &Xt[nx][(w * 32 + 16) * 32]);
      pA0 += 32; pA1 += 32; pX0 += 32; pX1 += 32;
      asm volatile("s_waitcnt vmcnt(4)" ::: "memory");
    } else {
      asm volatile("s_waitcnt vmcnt(0)" ::: "memory");
    }
    __builtin_amdgcn_s_barrier();           // all waves' cur-loads now visible
    __builtin_amdgcn_sched_barrier(0);      // keep ds_reads below the barrier
    s8 af[4], bfr[4];
    #pragma unroll
    for (int mi = 0; mi < 4; ++mi)
      af[mi] = *(const s8*)&At[cur][(wr + mi * 16 + l15) * 32 + qs];
    #pragma unroll
    for (int ni = 0; ni < 4; ++ni)
      bfr[ni] = *(const s8*)&Xt[cur][(wc + ni * 16 + l15) * 32 + qs];
    __builtin_amdgcn_s_setprio(1);
    #pragma unroll
    for (int mi = 0; mi < 4; ++mi)
      #pragma unroll
      for (int ni = 0; ni < 4; ++ni)
        acc[mi][ni] = __builtin_amdgcn_mfma_f32_16x16x32_bf16(af[mi], bfr[ni], acc[mi][ni], 0, 0, 0);
    __builtin_amdgcn_s_setprio(0);
    __builtin_amdgcn_s_barrier();           // reads of buf[cur] done -> next iter may overwrite
    cur ^= 1;
  }
  // C/D: col = lane&15, row = quad*4 + reg  [verified m89/m91]
  #pragma unroll
  for (int mi = 0; mi < 4; ++mi) {
    int rr = r0 + wr + mi * 16 + q * 4;
    #pragma unroll
    for (int ni = 0; ni < 4; ++ni) {
      int cc = j0 + wc + ni * 16 + l15;
      #pragma unroll
      for (int rg = 0; rg < 4; ++rg)
        Y[(size_t)(rr + rg) * CB + cc] = f2bf(acc[mi][ni][rg]);
    }
  }
}

// ---------------------------------------------------------------- Wm[n][o][KIP] bf16 = sum_d e[n,d] Wp[d,ki,o]
__global__ __launch_bounds__(256)
void k_wmat(const float* __restrict__ eg, const float* __restrict__ Wp, ushort* __restrict__ Wm) {
  constexpr int TRS = 36;  // Tr row stride (shorts)
  __shared__ float Wl[16 * 8 * 64];     // [d][kr][o]  32 KB
  __shared__ ushort Tr[8 * 64 * TRS];   // [n][o][36]
  const int t = threadIdx.x;
  const int n0 = blockIdx.x * 8;
  const int y = blockIdx.y;             // ki-quarter; y==3 covers kic 12..19 (incl. zero tail)
  const int o = t & 63, w = t >> 6;
  const int ng = w & 1, krh = (w >> 1) * 4;
  float er[4][16];
  #pragma unroll
  for (int j = 0; j < 4; ++j) {
    const float* ep = eg + (size_t)(n0 + ng * 4 + j) * D_;
    #pragma unroll
    for (int d = 0; d < D_; d += 4) {
      float4 v = *(const float4*)(ep + d);
      er[j][d] = v.x; er[j][d + 1] = v.y; er[j][d + 2] = v.z; er[j][d + 3] = v.w;
    }
  }
  const int ngroups = (y == 3) ? 2 : 1;
  for (int g = 0; g < ngroups; ++g) {
    const int kic0 = y * 4 + g * 4;
    for (int kk = 0; kk < 4; ++kk) {
      const int kic = kic0 + kk;
      __syncthreads();
      #pragma unroll
      for (int it = 0; it < 8; ++it) {
        int f = it * 256 + t;
        int d = f >> 7, rem = f & 127, kr = rem >> 4, o4 = rem & 15;
        int ki = kic * 8 + kr;
        float4 v;
        if (ki < KI) v = *(const float4*)&Wp[((size_t)d * KI + ki) * 64 + o4 * 4];
        else { v.x = 0.f; v.y = 0.f; v.z = 0.f; v.w = 0.f; }
        *(float4*)&Wl[f * 4] = v;
      }
      __syncthreads();
      float a[4][4];
      #pragma unroll
      for (int j = 0; j < 4; ++j)
        #pragma unroll
        for (int k = 0; k < 4; ++k) a[j][k] = 0.f;
      for (int d = 0; d < D_; ++d) {
        float w4[4];
        #pragma unroll
        for (int k = 0; k < 4; ++k) w4[k] = Wl[(d * 8 + krh + k) * 64 + o];
        #pragma unroll
        for (int j = 0; j < 4; ++j)
          #pragma unroll
          for (int k = 0; k < 4; ++k) a[j][k] = fmaf(er[j][d], w4[k], a[j][k]);
      }
      #pragma unroll
      for (int j = 0; j < 4; ++j) {
        ushort* tr = &Tr[((ng * 4 + j) * 64 + o) * TRS + kk * 8 + krh];
        *(uint*)&tr[0] = packbf(a[j][0], a[j][1]);
        *(uint*)&tr[2] = packbf(a[j][2], a[j][3]);
      }
    }
    __syncthreads();
    const int k0 = kic0 * 8;
    #pragma unroll
    for (int p = 0; p < 8; ++p) {
      int u = p * 256 + t;
      int nl = u >> 8, oo = (u >> 2) & 63, qq = u & 3;
      const ushort* tr = &Tr[(nl * 64 + oo) * TRS + qq * 8];
      uint2 lo = *(const uint2*)&tr[0];
      uint2 hi = *(const uint2*)&tr[4];
      uint4 vv; vv.x = lo.x; vv.y = lo.y; vv.z = hi.x; vv.w = hi.y;
      *(uint4*)&Wm[((size_t)(n0 + nl) * 64 + oo) * KIP + k0 + qq * 8] = vv;
    }
  }
}

// ---------------------------------------------------------------- per-node einsum via MFMA; B-frags direct from global Wm
template <int MODE>  // 0: sigmoid -> bf16 gate buf ; 1: tanh + GRU combine -> fp32 d_out
__global__ __launch_bounds__(256)
void k_einsum(const float* __restrict__ e, const ushort* __restrict__ Wm, const float* __restrict__ bp,
              const __hip_bfloat16* __restrict__ Y,
              const float* __restrict__ x, const float* __restrict__ state,
              const __hip_bfloat16* __restrict__ zbuf, const __hip_bfloat16* __restrict__ rbuf,
              void* __restrict__ outp) {
  constexpr int LDK = 168;
  constexpr int LDR = 72;
  __shared__ __align__(16) ushort xg[64 * LDK];
  __shared__ __align__(16) ushort res[64 * LDR];
  __shared__ float el[D_];
  __shared__ float bl[64];
  const int n = blockIdx.x, t = threadIdx.x;
  if (t < D_) el[t] = e[n * D_ + t];
  __syncthreads();
  if (t < 64) {
    float s = 0.f;
    #pragma unroll
    for (int d = 0; d < D_; ++d) s += el[d] * bp[d * 64 + t];
    bl[t] = s;
  }
  {
    const int b = t >> 2, j = t & 3;
    const size_t bn = (size_t)b * N_ + n;
    float sv[16];
    const float* sp = state + bn * 64 + j * 16;
    #pragma unroll
    for (int i = 0; i < 16; i += 4) {
      float4 v = *(const float4*)(sp + i);
      sv[i] = v.x; sv[i + 1] = v.y; sv[i + 2] = v.z; sv[i + 3] = v.w;
    }
    if (MODE) {
      const ushort* zp = (const ushort*)zbuf + bn * 64 + j * 16;
      uint4 z0 = *(const uint4*)&zp[0], z1 = *(const uint4*)&zp[8];
      uint zw[8] = {z0.x, z0.y, z0.z, z0.w, z1.x, z1.y, z1.z, z1.w};
      #pragma unroll
      for (int i = 0; i < 8; ++i) {
        sv[2 * i]     *= bf2f((ushort)(zw[i] & 0xffffu));
        sv[2 * i + 1] *= bf2f((ushort)(zw[i] >> 16));
      }
    }
    ushort* xr = &xg[b * LDK + 2 + j * 16];
    #pragma unroll
    for (int i = 0; i < 16; i += 2) {
      uint pk = packbf(sv[i], sv[i + 1]);
      *(uint*)&xr[i] = pk;
    }
    const ushort* yp = (const ushort*)Y + (size_t)n * CB + b * C_ + j * 16;
    uint* xy = (uint*)&xg[b * LDK + 66 + j * 16];
    #pragma unroll
    for (int i = 0; i < 8; ++i) xy[i] = *(const uint*)&yp[2 * i];
    if (j == 0) *(uint*)&xg[b * LDK + 130] = *(const uint*)&yp[64];
    if (t < 64) {
      const float* xp = x + ((size_t)t * N_ + n) * DIN;
      uint pk = packbf(xp[0], xp[1]);
      *(uint*)&xg[t * LDK] = pk;
    }
    ushort* pg = &xg[b * LDK + 132 + j * 7];
    #pragma unroll
    for (int i = 0; i < 7; ++i) pg[i] = 0;
  }
  __syncthreads();
  const int l15 = t & 15, q = (t >> 4) & 3, w = t >> 6;
  const int wm = (w >> 1) * 32, wn = (w & 1) * 32;
  const ushort* Wn = Wm + (size_t)n * (64 * KIP);
  f4 acc[2][2];
  acc[0][0] = acc[0][1] = acc[1][0] = acc[1][1] = (f4)0.0f;
  #pragma unroll
  for (int kk = 0; kk < KIP; kk += 32) {
    s8 af[2], bfr[2];
    #pragma unroll
    for (int mi = 0; mi < 2; ++mi) af[mi] = *(const s8*)&xg[(wm + mi * 16 + l15) * LDK + kk + q * 8];
    #pragma unroll
    for (int ni = 0; ni < 2; ++ni) bfr[ni] = *(const s8*)(Wn + (size_t)(wn + ni * 16 + l15) * KIP + kk + q * 8);
    #pragma unroll
    for (int mi = 0; mi < 2; ++mi)
      #pragma unroll
      for (int ni = 0; ni < 2; ++ni)
        acc[mi][ni] = __builtin_amdgcn_mfma_f32_16x16x32_bf16(af[mi], bfr[ni], acc[mi][ni], 0, 0, 0);
  }
  {
    float bl0 = bl[wn + l15], bl1 = bl[wn + 16 + l15];
    #pragma unroll
    for (int mi = 0; mi < 2; ++mi)
      #pragma unroll
      for (int ni = 0; ni < 2; ++ni) {
        float bb = ni ? bl1 : bl0;
        #pragma unroll
        for (int rg = 0; rg < 4; ++rg) {
          float v = acc[mi][ni][rg] + bb;
          float a;
          if (MODE == 0) a = 1.0f / (1.0f + __expf(-v));
          else           a = 1.0f - 2.0f / (__expf(2.0f * v) + 1.0f);
          res[(wm + mi * 16 + q * 4 + rg) * LDR + (wn + ni * 16 + l15)] = f2bf(a);
        }
      }
  }
  __syncthreads();
  {
    const int b = t >> 2, j = t & 3;
    const size_t gb = ((size_t)b * N_ + n) * 64 + j * 16;
    const ushort* rr = &res[b * LDR + j * 16];
    if (MODE == 0) {
      uint4 v0 = *(const uint4*)&rr[0];
      uint4 v1 = *(const uint4*)&rr[8];
      *(uint4*)((ushort*)outp + gb) = v0;
      *(uint4*)((ushort*)outp + gb + 8) = v1;
    } else {
      float* ob = (float*)outp;
      const float* stp = state + gb;
      const ushort* rp = (const ushort*)rbuf + gb;
      uint4 r0 = *(const uint4*)&rp[0], r1 = *(const uint4*)&rp[8];
      uint rw[8] = {r0.x, r0.y, r0.z, r0.w, r1.x, r1.y, r1.z, r1.w};
      #pragma unroll
      for (int i = 0; i < 16; i += 4) {
        float4 st = *(const float4*)(stp + i);
        float4 ov;
        float rv0 = bf2f((ushort)(rw[i / 2] & 0xffffu));
        float rv1 = bf2f((ushort)(rw[i / 2] >> 16));
        float rv2 = bf2f((ushort)(rw[i / 2 + 1] & 0xffffu));
        float rv3 = bf2f((ushort)(rw[i / 2 + 1] >> 16));
        ov.x = rv0 * st.x + (1.0f - rv0) * bf2f(rr[i]);
        ov.y = rv1 * st.y + (1.0f - rv1) * bf2f(rr[i + 1]);
        ov.z = rv2 * st.z + (1.0f - rv2) * bf2f(rr[i + 2]);
        ov.w = rv3 * st.w + (1.0f - rv3) * bf2f(rr[i + 3]);
        *(float4*)(ob + gb + i) = ov;
      }
    }
  }
}

// ----------------------------------------------------------------
extern "C" void kernel_launch(void* const* d_in, const int* in_sizes, int n_in,
                              void* d_out, int out_size, void* d_ws, size_t ws_size,
                              hipStream_t stream) {
  const float* x     = (const float*)d_in[0];
  const float* state = (const float*)d_in[1];
  const float* node  = (const float*)d_in[2];
  const float* timee = (const float*)d_in[3];
  const float* W_z = (const float*)d_in[4];
  const float* b_z = (const float*)d_in[5];
  const float* g_z = (const float*)d_in[6];
  const float* be_z = (const float*)d_in[7];
  const float* W_r = (const float*)d_in[8];
  const float* b_r = (const float*)d_in[9];
  const float* g_r = (const float*)d_in[10];
  const float* be_r = (const float*)d_in[11];
  const float* W_u = (const float*)d_in[12];
  const float* b_u = (const float*)d_in[13];
  const float* g_u = (const float*)d_in[14];
  const float* be_u = (const float*)d_in[15];

  constexpr size_t NN = (size_t)N_ * N_;
  constexpr size_t ND = (size_t)N_ * D_;
  // Workspace layout (bytes):
  char* ws = (char*)d_ws;
  float*           e  = (float*)(ws);                        //       0 :    393,216
  __hip_bfloat16*  A  = (__hip_bfloat16*)(ws + 393216);      //  25,165,824
  __hip_bfloat16*  XT = (__hip_bfloat16*)(ws + 25559040);    //  17,301,504
  __hip_bfloat16*  Y  = (__hip_bfloat16*)(ws + 42860544);    //  17,301,504 (Y_z; also reused for u)
  __hip_bfloat16*  zb = (__hip_bfloat16*)(ws + 60162048);    //  16,777,216
  __hip_bfloat16*  rb = (__hip_bfloat16*)(ws + 76939264);    //  16,777,216
  ushort*          ebf = (ushort*)(ws + 93716480);           //  196,608 (dead before Wm written)
  ushort*          Wm = (ushort*)(ws + 93716480);            //  41,943,040 (ends 135,659,520)
  __hip_bfloat16*  Yr = (__hip_bfloat16*)(ws + 135659520);   //  17,301,504 (big-ws only; ends 152,961,024)
  const size_t YRD = ((size_t)135659520 - 42860544) / 2;     // Y_z -> Y_r element delta
  const bool big = ws_size >= (size_t)152961024;

  float* out = (float*)d_out;

  k_e<<<8, 256, 0, stream>>>(node, timee, g_z, be_z, g_r, be_r, g_u, be_u, e, ebf);
  // fused S+softmax: no S materialization, one dispatch for all 3 gates
  k_attn<<<dim3(N_ / 16, 1, 3), 256, 0, stream>>>(ebf, A);
  k_buildX<0><<<dim3(32, 64), 256, 0, stream>>>(x, state, nullptr, XT);

  dim3 ggrid1(CB / 128, N_ / 128, 1);   // 528 blocks (%8==0)
  dim3 ggrid2(CB / 128, N_ / 128, 2);   // fused z+r: 1056 blocks (%8==0)
  dim3 wgrid(N_ / 8, 4);                // 1024 blocks

  if (big) {
    k_wmat<<<wgrid, 256, 0, stream>>>(e + 0 * ND, W_z, Wm);
    k_gemm<<<ggrid2, 256, 0, stream>>>(A, NN, XT, Y, YRD);                       // z->Y, r->Yr
    k_einsum<0><<<N_, 256, 0, stream>>>(e + 0 * ND, Wm, b_z, Y, x, state, nullptr, nullptr, (void*)zb);
    k_wmat<<<wgrid, 256, 0, stream>>>(e + 1 * ND, W_r, Wm);
    k_einsum<0><<<N_, 256, 0, stream>>>(e + 1 * ND, Wm, b_r, Yr, x, state, nullptr, nullptr, (void*)rb);
  } else {
    k_wmat<<<wgrid, 256, 0, stream>>>(e + 0 * ND, W_z, Wm);
    k_gemm<<<ggrid1, 256, 0, stream>>>(A, 0, XT, Y, 0);
    k_einsum<0><<<N_, 256, 0, stream>>>(e + 0 * ND, Wm, b_z, Y, x, state, nullptr, nullptr, (void*)zb);
    k_wmat<<<wgrid, 256, 0, stream>>>(e + 1 * ND, W_r, Wm);
    k_gemm<<<ggrid1, 256, 0, stream>>>(A + NN, 0, XT, Y, 0);
    k_einsum<0><<<N_, 256, 0, stream>>>(e + 1 * ND, Wm, b_r, Y, x, state, nullptr, nullptr, (void*)rb);
  }
  // gate u: cand = [x, z*state]
  k_buildX<1><<<dim3(32, 64), 256, 0, stream>>>(x, state, zb, XT);
  k_wmat<<<wgrid, 256, 0, stream>>>(e + 2 * ND, W_u, Wm);
  k_gemm<<<ggrid1, 256, 0, stream>>>(A + 2 * NN, 0, XT, Y, 0);
  k_einsum<1><<<N_, 256, 0, stream>>>(e + 2 * ND, Wm, b_u, Y, x, state, zb, rb, (void*)out);
}